// Round 18
// baseline (627.670 us; speedup 1.0000x reference)
//
#include <hip/hip_runtime.h>

#define T_STEPS 1024
#define B_TOT   512
#define VOCAB   1000
#define EMB     64
#define HID     64
#define GATES   256   // 4*HID

typedef float f4 __attribute__((ext_vector_type(4)));
typedef float f2 __attribute__((ext_vector_type(2)));

__device__ __forceinline__ float fast_rcp(float x)  { return __builtin_amdgcn_rcpf(x); }
__device__ __forceinline__ float fast_exp2(float x) { return __builtin_amdgcn_exp2f(x); }

__device__ __forceinline__ float sigmoid_f(float x) {
    return fast_rcp(1.0f + fast_exp2(-1.4426950408889634f * x));
}
__device__ __forceinline__ float tanh_f(float x) {
    float e = fast_exp2(2.8853900817779268f * x);
    return 1.0f - 2.0f * fast_rcp(e + 1.0f);
}

// packed fp32 FMA: 2 MACs/instr at full VALU issue rate (measured R14).
__device__ __forceinline__ void pk_fma_acc(f2& acc, f2 a, f2 b) {
    asm("v_pk_fma_f32 %0, %1, %2, %0" : "+v"(acc) : "v"(a), "v"(b));
}

// ---------------------------------------------------------------------------
// Kernel 1: zx table, layout [dir][vocab][unit][gate]:
//   thread j: u=j>>2, g=j&3, source col g*64+u, store at linear j ->
//   recurrent lane u reads ONE coalesced float4 = its unit's 4 gate zx.
// ---------------------------------------------------------------------------
__global__ __launch_bounds__(256, 4)
void zx_table_kernel(const float* __restrict__ emb,
                     const float* __restrict__ Wx_f, const float* __restrict__ b_f,
                     const float* __restrict__ Wx_b, const float* __restrict__ b_b,
                     float* __restrict__ zx_tab)
{
    const int bid = blockIdx.x;            // 0..1999
    const int dir = bid / VOCAB;
    const int v   = bid - dir * VOCAB;
    const int j   = threadIdx.x;
    const int g   = j & 3;
    const int u   = j >> 2;
    const int col = g * HID + u;

    const float* __restrict__ Wx = dir ? Wx_b : Wx_f;
    const float* __restrict__ bv = dir ? b_b  : b_f;

    __shared__ float4 x4[EMB / 4];
    if (j < EMB / 4) x4[j] = ((const float4*)emb)[v * (EMB / 4) + j];
    __syncthreads();

    float a0 = bv[col], a1 = 0.f, a2 = 0.f, a3 = 0.f;
#pragma unroll
    for (int q = 0; q < EMB / 4; ++q) {
        float4 xv = x4[q];
        a0 = fmaf(xv.x, Wx[(4 * q + 0) * GATES + col], a0);
        a1 = fmaf(xv.y, Wx[(4 * q + 1) * GATES + col], a1);
        a2 = fmaf(xv.z, Wx[(4 * q + 2) * GATES + col], a2);
        a3 = fmaf(xv.w, Wx[(4 * q + 3) * GATES + col], a3);
    }
    zx_tab[(dir * VOCAB + v) * GATES + j] = (a0 + a1) + (a2 + a3);
}

// ---------------------------------------------------------------------------
// Kernel 2: recurrence — K-SPLIT waves + pk_fma + single-barrier exchange.
// Block = 128 thr = 2 waves per (dir,row): 1024 blocks -> 2 waves/SIMD.
// Lane u owns hidden unit u (all 4 gates); wave w owns k in [32w, 32w+32):
//   dot: 64 pk_fma (4 gates x 16 f2 pairs; 128 weights = 64 f2 VGPRs)
//   exchange: ONE ds_write_b128 (f4 partials) + barrier + ONE ds_read_b128
//   z = (mine+other)+zx is commutative -> both waves compute bit-identical
//   c/h updates redundantly (R8-verified safe); each wave keeps its OWN
//   h copy in LDS and reads only its own k-range (8 x b128, same-wave
//   lgkmcnt ordering -> h needs NO barrier).
// Per step: 1 barrier (was 2), 1 cross-wave LDS round-trip (was 2).
// Masked steps (token==0, row-uniform): skip everything, state carries.
// ---------------------------------------------------------------------------
__global__ __launch_bounds__(128, 2)
void lstm_rec_kernel(const int* __restrict__ tokens,
                     const float* __restrict__ Wh_f,
                     const float* __restrict__ Wh_b,
                     const float* __restrict__ zx_tab,
                     float* __restrict__ out)
{
    const int bx  = blockIdx.x;        // 0..1023
    const int dir = bx >> 9;
    const int row = bx & 511;
    const int u   = threadIdx.x & 63;  // hidden unit
    const int w   = threadIdx.x >> 6;  // k-half: wave w owns k in [32w,32w+32)

    const float* __restrict__ Wh   = dir ? Wh_b : Wh_f;
    const f4*    __restrict__ zx4  = (const f4*)(zx_tab + dir * (VOCAB * GATES));
    const int*   __restrict__ trow = tokens + row * T_STEPS;

    // 128 weights as 64 f2: wt[g][m] = (Wh[32w+2m][g*64+u], Wh[32w+2m+1][..]).
    f2 wt[4][16];
#pragma unroll
    for (int g = 0; g < 4; ++g)
#pragma unroll
        for (int m = 0; m < 16; ++m) {
            f2 v;
            v.x = Wh[(32 * w + 2 * m)     * GATES + g * HID + u];
            v.y = Wh[(32 * w + 2 * m + 1) * GATES + g * HID + u];
            wt[g][m] = v;
        }

    __shared__ float hb[2][HID];       // per-wave h copies (bit-identical)
    __shared__ f4 part[2][2][HID];     // [parity][wave][unit] gate partials

    hb[w][u] = 0.0f;                   // each wave inits its own copy
    float c = 0.0f, h = 0.0f;
    int   par = 0;
    __syncthreads();

    // wave-uniform token chain + zx prefetch (one f4 per lane)
    int tokc = trow[dir ? (T_STEPS - 1) : 0];
    int tokn = trow[dir ? (T_STEPS - 2) : 1];
    f4  zxc  = zx4[tokc * (GATES / 4) + u];

    // own k-range of own h copy: hb[w][32w .. 32w+32) as 8 x f4
    const f4* __restrict__ hb4w = (const f4*)&hb[w][32 * w];

#pragma unroll 1
    for (int t = 0; t < T_STEPS; ++t) {
        // prefetches first: latency hides under the pk_fma block
        int t2   = (t + 2 < T_STEPS) ? (t + 2) : (T_STEPS - 1);
        int tokf = trow[dir ? (T_STEPS - 1 - t2) : t2];
        f4  zxn  = zx4[tokn * (GATES / 4) + u];

        if (tokc != 0) {               // row-uniform; padded steps carry state
            // ---- half-K dot for all 4 gates: 64 pk_fma, 4 acc chains ----
            __builtin_amdgcn_s_setprio(1);
            f2 a0; a0.x = 0.f; a0.y = 0.f;
            f2 a1 = a0, a2 = a0, a3 = a0;
#pragma unroll
            for (int q = 0; q < 8; ++q) {
                f4 hv = hb4w[q];                 // own-copy LDS broadcast
                f2 lo; lo.x = hv.x; lo.y = hv.y;
                f2 hi; hi.x = hv.z; hi.y = hv.w;
                pk_fma_acc(a0, lo, wt[0][2 * q]);
                pk_fma_acc(a1, lo, wt[1][2 * q]);
                pk_fma_acc(a2, lo, wt[2][2 * q]);
                pk_fma_acc(a3, lo, wt[3][2 * q]);
                pk_fma_acc(a0, hi, wt[0][2 * q + 1]);
                pk_fma_acc(a1, hi, wt[1][2 * q + 1]);
                pk_fma_acc(a2, hi, wt[2][2 * q + 1]);
                pk_fma_acc(a3, hi, wt[3][2 * q + 1]);
            }
            __builtin_amdgcn_s_setprio(0);
            f4 mine;
            mine[0] = a0.x + a0.y;
            mine[1] = a1.x + a1.y;
            mine[2] = a2.x + a2.y;
            mine[3] = a3.x + a3.y;

            // ---- single exchange: write f4, barrier, read other f4 ----
            part[par][w][u] = mine;
            __syncthreads();             // the ONLY barrier per step
            f4 other = part[par][w ^ 1][u];

            // z = (mine+other)+zx: commutative -> bit-identical on both waves
            float zi = (mine[0] + other[0]) + zxc[0];
            float zf = (mine[1] + other[1]) + zxc[1];
            float zg = (mine[2] + other[2]) + zxc[2];
            float zo = (mine[3] + other[3]) + zxc[3];

            float ig = sigmoid_f(zi);
            float fg = sigmoid_f(zf);
            float gg = tanh_f(zg);
            float og = sigmoid_f(zo);
            c = fmaf(fg, c, ig * gg);
            h = og * tanh_f(c);
            hb[w][u] = h;                // own copy; same-wave ordering only
            par ^= 1;
        }

        tokc = tokn; tokn = tokf; zxc = zxn;
    }

    if (w == 0)
        out[row * (2 * HID) + dir * HID + u] = h;
}

extern "C" void kernel_launch(void* const* d_in, const int* in_sizes, int n_in,
                              void* d_out, int out_size, void* d_ws, size_t ws_size,
                              hipStream_t stream) {
    const int*   tokens = (const int*)  d_in[0];
    const float* emb    = (const float*)d_in[1];
    const float* Wx_f   = (const float*)d_in[2];
    const float* Wh_f   = (const float*)d_in[3];
    const float* b_f    = (const float*)d_in[4];
    const float* Wx_b   = (const float*)d_in[5];
    const float* Wh_b   = (const float*)d_in[6];
    const float* b_b    = (const float*)d_in[7];
    float* out = (float*)d_out;

    float* zx_tab = (float*)d_ws;   // 2*1000*256*4 = 1.95 MB of d_ws

    hipLaunchKernelGGL(zx_table_kernel, dim3(2 * VOCAB), dim3(GATES), 0, stream,
                       emb, Wx_f, b_f, Wx_b, b_b, zx_tab);
    hipLaunchKernelGGL(lstm_rec_kernel, dim3(2 * B_TOT), dim3(128), 0, stream,
                       tokens, Wh_f, Wh_b, zx_tab, out);
}

// Round 22
// 566.731 us; speedup vs baseline: 1.1075x; 1.1075x over previous
//
#include <hip/hip_runtime.h>

#define T_STEPS 1024
#define B_TOT   512
#define VOCAB   1000
#define EMB     64
#define HID     64
#define GATES   256   // 4*HID

typedef float f4 __attribute__((ext_vector_type(4)));
typedef float f2 __attribute__((ext_vector_type(2)));

__device__ __forceinline__ float fast_rcp(float x)  { return __builtin_amdgcn_rcpf(x); }
__device__ __forceinline__ float fast_exp2(float x) { return __builtin_amdgcn_exp2f(x); }

__device__ __forceinline__ float sigmoid_f(float x) {
    return fast_rcp(1.0f + fast_exp2(-1.4426950408889634f * x));
}
__device__ __forceinline__ float tanh_f(float x) {
    float e = fast_exp2(2.8853900817779268f * x);
    return 1.0f - 2.0f * fast_rcp(e + 1.0f);
}

// packed fp32 FMA: 2 MACs/instr at full VALU issue rate (measured R14).
__device__ __forceinline__ void pk_fma_acc(f2& acc, f2 a, f2 b) {
    asm("v_pk_fma_f32 %0, %1, %2, %0" : "+v"(acc) : "v"(a), "v"(b));
}

// ---------------------------------------------------------------------------
// Kernel 1: zx table. Layout [dir][vocab][gatepair][unit][pair]:
//   thread j (0..255): p=j&1, u=(j>>1)&63, gp=j>>7, source col=(2gp+p)*64+u.
// Recurrent lane (gp,u) gathers float2 index tok*128 + gp*64 + u
//   = (z_gate(2gp)[u], z_gate(2gp+1)[u]) with bias + x-projection folded in.
// ---------------------------------------------------------------------------
__global__ __launch_bounds__(256, 4)
void zx_table_kernel(const float* __restrict__ emb,
                     const float* __restrict__ Wx_f, const float* __restrict__ b_f,
                     const float* __restrict__ Wx_b, const float* __restrict__ b_b,
                     float* __restrict__ zx_tab)
{
    const int bid = blockIdx.x;            // 0..1999
    const int dir = bid / VOCAB;
    const int v   = bid - dir * VOCAB;
    const int j   = threadIdx.x;
    const int p   = j & 1;
    const int u   = (j >> 1) & 63;
    const int w   = j >> 7;
    const int col = (2 * w + p) * HID + u;

    const float* __restrict__ Wx = dir ? Wx_b : Wx_f;
    const float* __restrict__ bv = dir ? b_b  : b_f;

    __shared__ float4 x4[EMB / 4];
    if (j < EMB / 4) x4[j] = ((const float4*)emb)[v * (EMB / 4) + j];
    __syncthreads();

    float a0 = bv[col], a1 = 0.f, a2 = 0.f, a3 = 0.f;
#pragma unroll
    for (int q = 0; q < EMB / 4; ++q) {
        float4 xv = x4[q];
        a0 = fmaf(xv.x, Wx[(4 * q + 0) * GATES + col], a0);
        a1 = fmaf(xv.y, Wx[(4 * q + 1) * GATES + col], a1);
        a2 = fmaf(xv.z, Wx[(4 * q + 2) * GATES + col], a2);
        a3 = fmaf(xv.w, Wx[(4 * q + 3) * GATES + col], a3);
    }
    zx_tab[(dir * VOCAB + v) * GATES + j] = (a0 + a1) + (a2 + a3);
}

// ---------------------------------------------------------------------------
// Kernel 2: recurrence — UNIT-SPLIT waves, gate-pair-split lane halves.
// Block = 128 thr = 2 waves per (dir,row): 1024 blocks -> 2 waves/SIMD.
// Lane l of wave w: unit u = 32w+(l&31), gate pair half=l>>5 (0: i,f; 1: g,o).
//   dot: 64 pk_fma for the 2 own gates (R16's exact structure), h read as
//        16 uniform b128 from parity buffer hb[p].
//   act exchange: __shfl_xor(v, 32) between lanes l and l^32 — SAME wave,
//        guaranteed-correct HIP intrinsic, no LDS array, no barrier.
//   update: both pair-lanes compute identical c/h (bit-identical inputs).
//   h exchange: write own unit to hb[p^1] -> ONE barrier -> next-step reads.
// tanh/sigmoid half-divergence folded branchlessly via tanh(x)=2*sig(2x)-1.
// Keeps setprio + branchless mask + unroll 2.
// ---------------------------------------------------------------------------
__global__ __launch_bounds__(128, 2)
void lstm_rec_kernel(const int* __restrict__ tokens,
                     const float* __restrict__ Wh_f,
                     const float* __restrict__ Wh_b,
                     const float* __restrict__ zx_tab,
                     float* __restrict__ out)
{
    const int bx   = blockIdx.x;        // 0..1023
    const int dir  = bx >> 9;
    const int row  = bx & 511;
    const int l    = threadIdx.x & 63;
    const int w    = threadIdx.x >> 6;  // wave: unit range [32w, 32w+32)
    const int half = l >> 5;            // gate pair: 0 -> i,f ; 1 -> g,o
    const int u    = w * 32 + (l & 31); // owned hidden unit

    const float* __restrict__ Wh   = dir ? Wh_b : Wh_f;
    const f2*    __restrict__ zx2  = (const f2*)(zx_tab + dir * (VOCAB * GATES));
    const int*   __restrict__ trow = tokens + row * T_STEPS;

    // 128 register-resident weights as 64 packed f2: own 2 gate columns.
    const int colA = (2 * half) * HID + u;
    const int colB = colA + HID;
    f2 whA2[HID / 2], whB2[HID / 2];
#pragma unroll
    for (int m = 0; m < HID / 2; ++m) {
        f2 a; a.x = Wh[(2 * m) * GATES + colA]; a.y = Wh[(2 * m + 1) * GATES + colA];
        whA2[m] = a;
        f2 b; b.x = Wh[(2 * m) * GATES + colB]; b.y = Wh[(2 * m + 1) * GATES + colB];
        whB2[m] = b;
    }

    // actA activation per half: half0 sigmoid(z), half1 tanh(z)=2*sig(2z)-1.
    const float kin  = half ? 2.0f : 1.0f;
    const float kmul = half ? 2.0f : 1.0f;
    const float kadd = half ? -1.0f : 0.0f;

    __shared__ float hb[2][HID];        // parity-double-buffered h (512 B)

    if (threadIdx.x < HID) { hb[0][threadIdx.x] = 0.0f; hb[1][threadIdx.x] = 0.0f; }
    float c = 0.0f, h = 0.0f;
    int   p = 0;
    __syncthreads();

    // wave-uniform token chain + zx prefetch (float2 per lane)
    int tokc = trow[dir ? (T_STEPS - 1) : 0];
    int tokn = trow[dir ? (T_STEPS - 2) : 1];
    f2  zxc  = zx2[tokc * 128 + half * 64 + u];

#pragma unroll 2
    for (int t = 0; t < T_STEPS; ++t) {
        // prefetches first: latency hides under the pk_fma block
        int t2   = (t + 2 < T_STEPS) ? (t + 2) : (T_STEPS - 1);
        int tokf = trow[dir ? (T_STEPS - 1 - t2) : t2];
        f2  zxn  = zx2[tokn * 128 + half * 64 + u];

        const f4* __restrict__ hb4 = (const f4*)&hb[p][0];

        // ---- two 64-dim dots as 64 pk_fma (4 packed chains) ----
        __builtin_amdgcn_s_setprio(1);
        f2 accA0; accA0.x = zxc.x; accA0.y = 0.f;
        f2 accA1; accA1.x = 0.f;   accA1.y = 0.f;
        f2 accB0; accB0.x = zxc.y; accB0.y = 0.f;
        f2 accB1; accB1.x = 0.f;   accB1.y = 0.f;
#pragma unroll
        for (int q = 0; q < HID / 4; ++q) {
            f4 hv = hb4[q];                      // uniform LDS broadcast
            f2 hlo; hlo.x = hv.x; hlo.y = hv.y;
            f2 hhi; hhi.x = hv.z; hhi.y = hv.w;
            pk_fma_acc(accA0, hlo, whA2[2 * q]);
            pk_fma_acc(accA1, hhi, whA2[2 * q + 1]);
            pk_fma_acc(accB0, hlo, whB2[2 * q]);
            pk_fma_acc(accB1, hhi, whB2[2 * q + 1]);
        }
        __builtin_amdgcn_s_setprio(0);
        float zA = (accA0.x + accA1.x) + (accA0.y + accA1.y);
        float zB = (accB0.x + accB1.x) + (accB0.y + accB1.y);

        // ---- own-gate activations (branchless across halves) ----
        float actA = fmaf(kmul, sigmoid_f(kin * zA), kadd);  // i : g
        float actB = sigmoid_f(zB);                          // f : o

        // ---- intra-wave act exchange: guaranteed-correct intrinsic ----
        float othA = __shfl_xor(actA, 32);
        float othB = __shfl_xor(actB, 32);

        // ---- redundant pair-lane update (bit-identical on both halves) ----
        float ig = half ? othA : actA;
        float fg = half ? othB : actB;
        float gg = half ? actA : othA;
        float og = half ? actB : othB;
        float c_new = fmaf(fg, c, ig * gg);
        float h_new = og * tanh_f(c_new);
        bool  m = (tokc != 0);           // Keras mask_zero (row-uniform)
        c = m ? c_new : c;
        h = m ? h_new : h;

        hb[p ^ 1][u] = h;                // pair-duplicate write (same value)
        __syncthreads();                 // the ONLY barrier per step
        p ^= 1;

        tokc = tokn; tokn = tokf; zxc = zxn;
    }

    if (!half)
        out[row * (2 * HID) + dir * HID + u] = h;
}

extern "C" void kernel_launch(void* const* d_in, const int* in_sizes, int n_in,
                              void* d_out, int out_size, void* d_ws, size_t ws_size,
                              hipStream_t stream) {
    const int*   tokens = (const int*)  d_in[0];
    const float* emb    = (const float*)d_in[1];
    const float* Wx_f   = (const float*)d_in[2];
    const float* Wh_f   = (const float*)d_in[3];
    const float* b_f    = (const float*)d_in[4];
    const float* Wx_b   = (const float*)d_in[5];
    const float* Wh_b   = (const float*)d_in[6];
    const float* b_b    = (const float*)d_in[7];
    float* out = (float*)d_out;

    float* zx_tab = (float*)d_ws;   // 2*1000*256*4 = 1.95 MB of d_ws

    hipLaunchKernelGGL(zx_table_kernel, dim3(2 * VOCAB), dim3(GATES), 0, stream,
                       emb, Wx_f, b_f, Wx_b, b_b, zx_tab);
    hipLaunchKernelGGL(lstm_rec_kernel, dim3(2 * B_TOT), dim3(128), 0, stream,
                       tokens, Wh_f, Wh_b, zx_tab, out);
}